// Round 1
// baseline (124.303 us; speedup 1.0000x reference)
//
#include <hip/hip_runtime.h>

// Problem constants (fixed by setup_inputs in the reference):
//   candidate_pts (2,128,10,3) -> queries (B=2, S=1280, 3)
//   src_keypts    (2,128,3)    -> UNUSED by reference
//   tgt_pts_xyz   (2,16384,3)
//   tgt_deep_feat (2,16384,32)
// out (2,128,10,32,35) fp32 = (B, S, K=32, 3+F)
constexpr int B_  = 2;
constexpr int S_  = 1280;     // 128 * 10
constexpr int N_  = 16384;
constexpr int F_  = 32;
constexpr int K_  = 32;
constexpr int CH_ = 3 + F_;   // 35
constexpr float R2_ = 4.0f;   // D_RADIUS^2

// One wave (64 threads) per query. Phase 1: ballot-scan the reference points
// in ascending index order, collecting the first K_ with dist^2 <= R2_.
// Phase 2: gather xyz*0.5 and feats, write 1120 floats coalesced.
__global__ __launch_bounds__(64) void ballquery_gather(
    const float* __restrict__ cand,   // (B,S,3)
    const float* __restrict__ xyz,    // (B,N,3)
    const float* __restrict__ feat,   // (B,N,F)
    float* __restrict__ out)          // (B,S,K,CH)
{
    const int q    = blockIdx.x;        // 0 .. B*S-1
    const int b    = q / S_;
    const int lane = threadIdx.x;       // 0 .. 63

    const float qx = cand[q * 3 + 0];
    const float qy = cand[q * 3 + 1];
    const float qz = cand[q * 3 + 2];
    // Replicate reference op order exactly; _rn intrinsics forbid FMA fusion.
    const float qq = __fadd_rn(__fadd_rn(__fmul_rn(qx, qx), __fmul_rn(qy, qy)),
                               __fmul_rn(qz, qz));

    const float* __restrict__ xb = xyz  + (size_t)b * N_ * 3;
    const float* __restrict__ fb = feat + (size_t)b * N_ * F_;

    __shared__ int sidx[K_];

    int found = 0;  // wave-uniform
    for (int base = 0; base < N_ && found < K_; base += 64) {
        const int n = base + lane;      // N_ % 64 == 0 -> always in range
        const float x0 = xb[n * 3 + 0];
        const float x1 = xb[n * 3 + 1];
        const float x2 = xb[n * 3 + 2];
        const float dot = __fadd_rn(__fadd_rn(__fmul_rn(qx, x0), __fmul_rn(qy, x1)),
                                    __fmul_rn(qz, x2));
        const float xx  = __fadd_rn(__fadd_rn(__fmul_rn(x0, x0), __fmul_rn(x1, x1)),
                                    __fmul_rn(x2, x2));
        // sqr = (qq - 2*dot) + xx   (matches  sum1 - 2*einsum + sum2)
        const float sqr = __fadd_rn(__fsub_rn(qq, __fmul_rn(2.0f, dot)), xx);
        const bool pred = !(sqr > R2_);   // kept iff sqr <= R2 (NaN-keeping like ref)

        const unsigned long long m = __ballot(pred);
        const int prefix = __popcll(m & ((1ull << lane) - 1ull));
        if (pred && (found + prefix) < K_)
            sidx[found + prefix] = n;
        found += __popcll(m);
    }
    __syncthreads();

    // Pad trailing slots with the first neighbor (reference semantics).
    // found==0 can't happen with this data; JAX OOB-gather clamps N -> N-1.
    const int first = (found > 0) ? sidx[0] : (N_ - 1);
    if (lane < K_ && lane >= found)
        sidx[lane] = first;
    __syncthreads();

    float* __restrict__ ob = out + (size_t)q * (K_ * CH_);
    #pragma unroll 4
    for (int t = lane; t < K_ * CH_; t += 64) {
        const int k = t / CH_;
        const int c = t - k * CH_;
        const int n = sidx[k];
        ob[t] = (c < 3) ? xb[n * 3 + c] * 0.5f
                        : fb[(size_t)n * F_ + (c - 3)];
    }
}

extern "C" void kernel_launch(void* const* d_in, const int* in_sizes, int n_in,
                              void* d_out, int out_size, void* d_ws, size_t ws_size,
                              hipStream_t stream) {
    const float* cand = (const float*)d_in[0];   // candidate_pts
    // d_in[1] = src_keypts — unused by the reference
    const float* xyz  = (const float*)d_in[2];   // tgt_pts_xyz
    const float* feat = (const float*)d_in[3];   // tgt_deep_feat_pts
    float* out = (float*)d_out;

    ballquery_gather<<<B_ * S_, 64, 0, stream>>>(cand, xyz, feat, out);
}

// Round 2
// 82.489 us; speedup vs baseline: 1.5069x; 1.5069x over previous
//
#include <hip/hip_runtime.h>

// Problem constants (fixed by setup_inputs in the reference):
//   candidate_pts (2,128,10,3) -> queries (B=2, S=1280, 3)
//   src_keypts    (2,128,3)    -> UNUSED by reference
//   tgt_pts_xyz   (2,16384,3)
//   tgt_deep_feat (2,16384,32)
// out (2,128,10,32,35) fp32 = (B, S, K=32, 3+F)
constexpr int B_  = 2;
constexpr int S_  = 1280;     // 128 * 10
constexpr int N_  = 16384;
constexpr int F_  = 32;
constexpr int K_  = 32;
constexpr int CH_ = 3 + F_;   // 35
constexpr float R2_ = 4.0f;   // D_RADIUS^2

// Scan pipelining: groups of CPG chunks (64 points each), double-buffered in
// registers so the next group's loads are in flight while the current group
// is ballot-processed. Exit check only at group granularity -> the serial
// dependence (ballot -> continue?) is amortized over 512 points.
constexpr int CPG  = 8;            // chunks per group
constexpr int GPTS = CPG * 64;     // 512 points per group
constexpr int NG   = N_ / GPTS;    // 32 groups

__global__ __launch_bounds__(64) void ballquery_gather(
    const float* __restrict__ cand,   // (B,S,3)
    const float* __restrict__ xyz,    // (B,N,3)
    const float* __restrict__ feat,   // (B,N,F)
    float* __restrict__ out)          // (B,S,K,CH)
{
    const int q    = blockIdx.x;        // 0 .. B*S-1
    const int b    = q / S_;
    const int lane = threadIdx.x;       // 0 .. 63

    const float qx = cand[q * 3 + 0];
    const float qy = cand[q * 3 + 1];
    const float qz = cand[q * 3 + 2];
    // Replicate reference op order exactly; _rn intrinsics forbid FMA fusion.
    const float qq = __fadd_rn(__fadd_rn(__fmul_rn(qx, qx), __fmul_rn(qy, qy)),
                               __fmul_rn(qz, qz));

    const float* __restrict__ xb = xyz  + (size_t)b * N_ * 3;
    const float* __restrict__ fb = feat + (size_t)b * N_ * F_;

    __shared__ int sidx[K_];

    int found = 0;  // wave-uniform

    float ax[CPG], ay[CPG], az[CPG];
    float bx[CPG], by[CPG], bz[CPG];

    auto loadGroup = [&](int g, float (&px)[CPG], float (&py)[CPG],
                         float (&pz)[CPG]) {
        #pragma unroll
        for (int c = 0; c < CPG; ++c) {
            const int n = (g * CPG + c) * 64 + lane;   // always < N_
            px[c] = xb[n * 3 + 0];
            py[c] = xb[n * 3 + 1];
            pz[c] = xb[n * 3 + 2];
        }
    };

    auto processGroup = [&](int g, const float (&px)[CPG], const float (&py)[CPG],
                            const float (&pz)[CPG]) {
        #pragma unroll
        for (int c = 0; c < CPG; ++c) {
            const int n = (g * CPG + c) * 64 + lane;
            const float x0 = px[c], x1 = py[c], x2 = pz[c];
            const float dot = __fadd_rn(__fadd_rn(__fmul_rn(qx, x0), __fmul_rn(qy, x1)),
                                        __fmul_rn(qz, x2));
            const float xx  = __fadd_rn(__fadd_rn(__fmul_rn(x0, x0), __fmul_rn(x1, x1)),
                                        __fmul_rn(x2, x2));
            // sqr = (qq - 2*dot) + xx   (matches  sum1 - 2*einsum + sum2)
            const float sqr = __fadd_rn(__fsub_rn(qq, __fmul_rn(2.0f, dot)), xx);
            const bool pred = !(sqr > R2_);   // kept iff sqr <= R2 (NaN-keeping)

            const unsigned long long m = __ballot(pred);
            const int prefix = __popcll(m & ((1ull << lane) - 1ull));
            if (pred && (found + prefix) < K_)
                sidx[found + prefix] = n;
            found += __popcll(m);
        }
    };

    loadGroup(0, ax, ay, az);
    for (int g = 0; g < NG && found < K_; g += 2) {
        const int g1 = (g + 1 < NG) ? g + 1 : NG - 1;   // clamped speculative
        loadGroup(g1, bx, by, bz);
        processGroup(g, ax, ay, az);
        if (found >= K_ || g + 1 >= NG) break;
        const int g2 = (g + 2 < NG) ? g + 2 : NG - 1;
        loadGroup(g2, ax, ay, az);
        processGroup(g + 1, bx, by, bz);
    }
    __syncthreads();

    // Pad trailing slots with the first neighbor (reference semantics).
    // found==0 can't happen with this data; JAX OOB-gather clamps N -> N-1.
    const int first = (found > 0) ? sidx[0] : (N_ - 1);
    if (lane < K_ && lane >= found)
        sidx[lane] = first;
    __syncthreads();

    float* __restrict__ ob = out + (size_t)q * (K_ * CH_);
    #pragma unroll 4
    for (int t = lane; t < K_ * CH_; t += 64) {
        const int k = t / CH_;
        const int c = t - k * CH_;
        const int n = sidx[k];
        ob[t] = (c < 3) ? xb[n * 3 + c] * 0.5f
                        : fb[(size_t)n * F_ + (c - 3)];
    }
}

extern "C" void kernel_launch(void* const* d_in, const int* in_sizes, int n_in,
                              void* d_out, int out_size, void* d_ws, size_t ws_size,
                              hipStream_t stream) {
    const float* cand = (const float*)d_in[0];   // candidate_pts
    // d_in[1] = src_keypts — unused by the reference
    const float* xyz  = (const float*)d_in[2];   // tgt_pts_xyz
    const float* feat = (const float*)d_in[3];   // tgt_deep_feat_pts
    float* out = (float*)d_out;

    ballquery_gather<<<B_ * S_, 64, 0, stream>>>(cand, xyz, feat, out);
}